// Round 1
// baseline (306.494 us; speedup 1.0000x reference)
//
#include <hip/hip_runtime.h>

#define S_LEN 2048
#define NF 1024
#define NH 16
#define HD 64
#define NB 2
#define M_TOT 4096  // NB*S_LEN

typedef __bf16 bf16x8 __attribute__((ext_vector_type(8)));
typedef float f32x4 __attribute__((ext_vector_type(4)));
typedef unsigned short u16;

__device__ __forceinline__ u16 f2bf(float f) {
  union { float f; unsigned u; } v; v.f = f;
  unsigned r = v.u + 0x7FFFu + ((v.u >> 16) & 1u);
  return (u16)(r >> 16);
}

__device__ __forceinline__ f32x4 mfma16(bf16x8 a, bf16x8 b, f32x4 c) {
  return __builtin_amdgcn_mfma_f32_16x16x32_bf16(a, b, c, 0, 0, 0);
}

// ---- cast fp32 -> bf16, 4 elems/thread ----
__global__ void __launch_bounds__(256) cast_kernel(const float* __restrict__ in,
                                                   u16* __restrict__ out) {
  int i = (blockIdx.x * 256 + threadIdx.x) * 4;
  float4 v = *(const float4*)(in + i);
  ushort4 o;
  o.x = f2bf(v.x); o.y = f2bf(v.y); o.z = f2bf(v.z); o.w = f2bf(v.w);
  *(ushort4*)(out + i) = o;
}

// ---- rope table: tab[(b*S+s)*32 + p] = (sin, cos) ----
__global__ void __launch_bounds__(256) rope_table_kernel(const int* __restrict__ positions,
                                                         float2* __restrict__ tab) {
  int idx = blockIdx.x * 256 + threadIdx.x;  // < NB*S_LEN*32
  int p = idx & 31;
  int bs = idx >> 5;
  float pos = (float)positions[bs];
  float ang = pos / __powf(10000.0f, (float)p * (1.0f / 32.0f));
  float sn, cs;
  sincosf(ang, &sn, &cs);
  tab[idx] = make_float2(sn, cs);
}

// ---- weight transpose + cast: Wt[n][k] = W[k][n] ----
__global__ void __launch_bounds__(256) wtrans_kernel(const float* __restrict__ W,
                                                     u16* __restrict__ Wt) {
  __shared__ float t[32][33];
  int n0 = blockIdx.x * 32, k0 = blockIdx.y * 32;
  int tx = threadIdx.x, ty0 = threadIdx.y;
#pragma unroll
  for (int i = 0; i < 4; i++) {
    int ty = ty0 + i * 8;
    t[ty][tx] = W[(size_t)(k0 + ty) * NF + n0 + tx];
  }
  __syncthreads();
#pragma unroll
  for (int i = 0; i < 4; i++) {
    int ty = ty0 + i * 8;
    Wt[(size_t)(n0 + ty) * NF + k0 + tx] = f2bf(t[tx][ty]);
  }
}

#define LDSP 40  // padded LDS k-stride (32 + 8 bf16): 2-way bank aliasing only

// 128x128 tile bf16 GEMM core: C = A[M,K] * Bt[N,K]^T, K=1024
__device__ __forceinline__ void mm_core(const u16* __restrict__ A, const u16* __restrict__ Bt,
                                        int m0, int n0, u16* As, u16* Bs, f32x4 acc[4][4]) {
  const int tid = threadIdx.x;
  const int lane = tid & 63, w = tid >> 6;
  const int l15 = lane & 15, quad = lane >> 4;
  const int wr = w >> 1, wc = w & 1;
#pragma unroll
  for (int i = 0; i < 4; i++)
#pragma unroll
    for (int j = 0; j < 4; j++) {
      f32x4 z = {0.f, 0.f, 0.f, 0.f};
      acc[i][j] = z;
    }
  for (int k0 = 0; k0 < NF; k0 += 32) {
#pragma unroll
    for (int i = 0; i < 2; i++) {
      int c = tid + i * 256;
      int row = c >> 2, cc = (c & 3) * 8;
      *(uint4*)&As[row * LDSP + cc] = *(const uint4*)&A[(size_t)(m0 + row) * NF + k0 + cc];
      *(uint4*)&Bs[row * LDSP + cc] = *(const uint4*)&Bt[(size_t)(n0 + row) * NF + k0 + cc];
    }
    __syncthreads();
    bf16x8 af[4], bfr[4];
#pragma unroll
    for (int i = 0; i < 4; i++)
      af[i] = *(const bf16x8*)&As[(wr * 64 + i * 16 + l15) * LDSP + quad * 8];
#pragma unroll
    for (int j = 0; j < 4; j++)
      bfr[j] = *(const bf16x8*)&Bs[(wc * 64 + j * 16 + l15) * LDSP + quad * 8];
#pragma unroll
    for (int i = 0; i < 4; i++)
#pragma unroll
      for (int j = 0; j < 4; j++)
        acc[i][j] = mfma16(af[i], bfr[j], acc[i][j]);
    __syncthreads();
  }
}

// ---- fused QKV projection: z=0 -> q (rope), z=1 -> k (rope), z=2 -> v (transposed out) ----
__global__ void __launch_bounds__(256) gemm_qkv_kernel(
    const u16* __restrict__ xb,
    const u16* __restrict__ wtq, const u16* __restrict__ wtk, const u16* __restrict__ wtv,
    const float* __restrict__ bq, const float* __restrict__ bk, const float* __restrict__ bv,
    const float2* __restrict__ rtab,
    u16* __restrict__ qo, u16* __restrict__ ko, u16* __restrict__ vto) {
  __shared__ u16 As[128 * LDSP], Bs[128 * LDSP];
  const int z = blockIdx.z;
  const u16* Wt = (z == 0) ? wtq : (z == 1) ? wtk : wtv;
  const float* bias = (z == 0) ? bq : (z == 1) ? bk : bv;
  const int m0 = blockIdx.y * 128, n0 = blockIdx.x * 128;
  f32x4 acc[4][4];
  mm_core(xb, Wt, m0, n0, As, Bs, acc);
  const int tid = threadIdx.x;
  const int lane = tid & 63, w = tid >> 6;
  const int l15 = lane & 15, quad = lane >> 4;
  const int wr = w >> 1, wc = w & 1;
  if (z < 2) {
    u16* out = (z == 0) ? qo : ko;
#pragma unroll
    for (int i = 0; i < 4; i++) {
#pragma unroll
      for (int r = 0; r < 4; r++) {
        int gm = m0 + wr * 64 + i * 16 + quad * 4 + r;  // = b*S + s
        int b = gm >> 11, s = gm & 2047;
#pragma unroll
        for (int j = 0; j < 2; j++) {
          int col1 = n0 + wc * 64 + j * 16 + l15;  // d = p < 32 within head
          int p = j * 16 + l15;
          float2 sc = rtab[gm * 32 + p];
          float x1 = acc[i][j][r] + bias[col1];
          float x2 = acc[i][j + 2][r] + bias[col1 + 32];
          float o1 = x1 * sc.y - x2 * sc.x;
          float o2 = x2 * sc.y + x1 * sc.x;
          int h = col1 >> 6;
          size_t base = ((size_t)((b * NH + h) * S_LEN + s)) * HD;
          out[base + p] = f2bf(o1);
          out[base + p + 32] = f2bf(o2);
        }
      }
    }
  } else {
    // v: write transposed [bh][d][s]; 4 acc regs = 4 consecutive s -> ushort4
#pragma unroll
    for (int i = 0; i < 4; i++) {
      int gm0 = m0 + wr * 64 + i * 16 + quad * 4;
      int b = gm0 >> 11, s0 = gm0 & 2047;
#pragma unroll
      for (int j = 0; j < 4; j++) {
        int col = n0 + wc * 64 + j * 16 + l15;
        int h = col >> 6, d = col & 63;
        float bb = bias[col];
        ushort4 pk;
        pk.x = f2bf(acc[i][j][0] + bb);
        pk.y = f2bf(acc[i][j][1] + bb);
        pk.z = f2bf(acc[i][j][2] + bb);
        pk.w = f2bf(acc[i][j][3] + bb);
        *(ushort4*)&vto[((size_t)((b * NH + h) * HD + d)) * S_LEN + s0] = pk;
      }
    }
  }
}

// ---- output projection: fp32 out ----
__global__ void __launch_bounds__(256) gemm_o_kernel(const u16* __restrict__ ab,
                                                     const u16* __restrict__ wto,
                                                     const float* __restrict__ bo,
                                                     float* __restrict__ out) {
  __shared__ u16 As[128 * LDSP], Bs[128 * LDSP];
  const int m0 = blockIdx.y * 128, n0 = blockIdx.x * 128;
  f32x4 acc[4][4];
  mm_core(ab, wto, m0, n0, As, Bs, acc);
  const int tid = threadIdx.x;
  const int lane = tid & 63, w = tid >> 6;
  const int l15 = lane & 15, quad = lane >> 4;
  const int wr = w >> 1, wc = w & 1;
#pragma unroll
  for (int i = 0; i < 4; i++) {
#pragma unroll
    for (int j = 0; j < 4; j++) {
      int col = n0 + wc * 64 + j * 16 + l15;
      float bb = bo[col];
#pragma unroll
      for (int r = 0; r < 4; r++) {
        int gm = m0 + wr * 64 + i * 16 + quad * 4 + r;
        out[(size_t)gm * NF + col] = acc[i][j][r] + bb;
      }
    }
  }
}

// ---- flash attention, causal, 64-row Q-tile per block ----
#define AP 72  // padded row stride for 64-wide tiles

__global__ void __launch_bounds__(256) attn_kernel(const u16* __restrict__ qb,
                                                   const u16* __restrict__ kb,
                                                   const u16* __restrict__ vtb,
                                                   u16* __restrict__ ob) {
  __shared__ u16 qs[64 * AP], ks[64 * AP], vs[64 * AP];
  __shared__ u16 ps[4][16 * AP];
  const int qt = blockIdx.x, bh = blockIdx.y;
  const int q0 = qt * 64;
  const int tid = threadIdx.x;
  const int lane = tid & 63, w = tid >> 6;
  const int l15 = lane & 15, quad = lane >> 4;

#pragma unroll
  for (int i = 0; i < 2; i++) {
    int c = tid + i * 256;
    int row = c >> 3, cc = (c & 7) * 8;
    *(uint4*)&qs[row * AP + cc] = *(const uint4*)&qb[((size_t)bh * S_LEN + q0 + row) * HD + cc];
  }
  __syncthreads();
  bf16x8 aq0 = *(const bf16x8*)&qs[(w * 16 + l15) * AP + quad * 8];
  bf16x8 aq1 = *(const bf16x8*)&qs[(w * 16 + l15) * AP + 32 + quad * 8];

  float mrun[4], lrun[4];
  f32x4 Oa[4];
#pragma unroll
  for (int r = 0; r < 4; r++) { mrun[r] = -1e30f; lrun[r] = 0.f; }
#pragma unroll
  for (int t = 0; t < 4; t++) { f32x4 z = {0.f, 0.f, 0.f, 0.f}; Oa[t] = z; }

  for (int kt = 0; kt <= qt; kt++) {
    int k0 = kt * 64;
    __syncthreads();  // prior iter's reads of ks/vs done before restage
#pragma unroll
    for (int i = 0; i < 2; i++) {
      int c = tid + i * 256;
      int row = c >> 3, cc = (c & 7) * 8;
      *(uint4*)&ks[row * AP + cc] = *(const uint4*)&kb[((size_t)bh * S_LEN + k0 + row) * HD + cc];
      *(uint4*)&vs[row * AP + cc] = *(const uint4*)&vtb[((size_t)bh * HD + row) * S_LEN + k0 + cc];
    }
    __syncthreads();
    // QK^T: scores for this wave's 16 q-rows x 64 k-cols
    f32x4 sf[4];
#pragma unroll
    for (int t = 0; t < 4; t++) {
      bf16x8 bk0 = *(const bf16x8*)&ks[(t * 16 + l15) * AP + quad * 8];
      bf16x8 bk1 = *(const bf16x8*)&ks[(t * 16 + l15) * AP + 32 + quad * 8];
      f32x4 zz = {0.f, 0.f, 0.f, 0.f};
      zz = mfma16(aq0, bk0, zz);
      zz = mfma16(aq1, bk1, zz);
      sf[t] = zz;
    }
    const bool diag = (kt == qt);
#pragma unroll
    for (int t = 0; t < 4; t++)
#pragma unroll
      for (int r = 0; r < 4; r++) {
        float v = sf[t][r] * 0.125f;  // 1/sqrt(64)
        if (diag && (k0 + t * 16 + l15 > q0 + w * 16 + quad * 4 + r)) v = -1e30f;
        sf[t][r] = v;
      }
    // online softmax per row (row r lives in the 16 lanes of this quad-group)
    float alph[4];
#pragma unroll
    for (int r = 0; r < 4; r++) {
      float mx = fmaxf(fmaxf(sf[0][r], sf[1][r]), fmaxf(sf[2][r], sf[3][r]));
#pragma unroll
      for (int off = 1; off < 16; off <<= 1) mx = fmaxf(mx, __shfl_xor(mx, off, 64));
      float mnew = fmaxf(mrun[r], mx);
      alph[r] = __expf(mrun[r] - mnew);
      float rs = 0.f;
#pragma unroll
      for (int t = 0; t < 4; t++) {
        float pv = __expf(sf[t][r] - mnew);
        sf[t][r] = pv;
        rs += pv;
      }
#pragma unroll
      for (int off = 1; off < 16; off <<= 1) rs += __shfl_xor(rs, off, 64);
      lrun[r] = alph[r] * lrun[r] + rs;
      mrun[r] = mnew;
    }
#pragma unroll
    for (int t = 0; t < 4; t++)
#pragma unroll
      for (int r = 0; r < 4; r++) Oa[t][r] *= alph[r];
    // P: C-layout -> LDS -> A-layout (per-wave region)
#pragma unroll
    for (int t = 0; t < 4; t++)
#pragma unroll
      for (int r = 0; r < 4; r++)
        ps[w][(quad * 4 + r) * AP + t * 16 + l15] = f2bf(sf[t][r]);
    __syncthreads();
    bf16x8 ap0 = *(const bf16x8*)&ps[w][l15 * AP + quad * 8];
    bf16x8 ap1 = *(const bf16x8*)&ps[w][l15 * AP + 32 + quad * 8];
#pragma unroll
    for (int t = 0; t < 4; t++) {
      bf16x8 bv0 = *(const bf16x8*)&vs[(t * 16 + l15) * AP + quad * 8];
      bf16x8 bv1 = *(const bf16x8*)&vs[(t * 16 + l15) * AP + 32 + quad * 8];
      Oa[t] = mfma16(ap0, bv0, Oa[t]);
      Oa[t] = mfma16(ap1, bv1, Oa[t]);
    }
  }
  // epilogue: normalize, write [b][s][h*64+d] bf16 for the output GEMM
  const int b = bh >> 4, h = bh & 15;
#pragma unroll
  for (int r = 0; r < 4; r++) {
    int sq = q0 + w * 16 + quad * 4 + r;
    float inv = 1.f / lrun[r];
    size_t rowb = ((size_t)(b * S_LEN + sq)) * NF + h * HD;
#pragma unroll
    for (int t = 0; t < 4; t++)
      ob[rowb + t * 16 + l15] = f2bf(Oa[t][r] * inv);
  }
}

extern "C" void kernel_launch(void* const* d_in, const int* in_sizes, int n_in,
                              void* d_out, int out_size, void* d_ws, size_t ws_size,
                              hipStream_t stream) {
  const float* x  = (const float*)d_in[0];
  const int* pos  = (const int*)d_in[1];
  const float* Wq = (const float*)d_in[2];
  const float* bq = (const float*)d_in[3];
  const float* Wk = (const float*)d_in[4];
  const float* bk = (const float*)d_in[5];
  const float* Wv = (const float*)d_in[6];
  const float* bv = (const float*)d_in[7];
  const float* Wo = (const float*)d_in[8];
  const float* bo = (const float*)d_in[9];
  float* out = (float*)d_out;

  u16* xb  = (u16*)d_ws;                    // [M][F] bf16, reused later as attn out
  u16* wtq = xb + (size_t)M_TOT * NF;
  u16* wtk = wtq + (size_t)NF * NF;
  u16* wtv = wtk + (size_t)NF * NF;
  u16* wto = wtv + (size_t)NF * NF;
  u16* qb  = wto + (size_t)NF * NF;         // [bh][s][d]
  u16* kb  = qb + (size_t)M_TOT * NF;       // [bh][s][d]
  u16* vtb = kb + (size_t)M_TOT * NF;       // [bh][d][s]
  float2* rtab = (float2*)(vtb + (size_t)M_TOT * NF);
  u16* attnb = xb;  // alias: xb no longer needed after QKV GEMM

  cast_kernel<<<dim3(M_TOT * NF / 1024), 256, 0, stream>>>(x, xb);
  rope_table_kernel<<<dim3(NB * S_LEN * 32 / 256), 256, 0, stream>>>(pos, rtab);
  wtrans_kernel<<<dim3(32, 32), dim3(32, 8), 0, stream>>>(Wq, wtq);
  wtrans_kernel<<<dim3(32, 32), dim3(32, 8), 0, stream>>>(Wk, wtk);
  wtrans_kernel<<<dim3(32, 32), dim3(32, 8), 0, stream>>>(Wv, wtv);
  wtrans_kernel<<<dim3(32, 32), dim3(32, 8), 0, stream>>>(Wo, wto);
  gemm_qkv_kernel<<<dim3(8, 32, 3), 256, 0, stream>>>(xb, wtq, wtk, wtv, bq, bk, bv,
                                                      rtab, qb, kb, vtb);
  attn_kernel<<<dim3(32, 32), 256, 0, stream>>>(qb, kb, vtb, attnb);
  gemm_o_kernel<<<dim3(8, 32), 256, 0, stream>>>(attnb, wto, bo, out);
}

// Round 2
// 241.448 us; speedup vs baseline: 1.2694x; 1.2694x over previous
//
#include <hip/hip_runtime.h>

#define S_LEN 2048
#define NF 1024
#define NH 16
#define HD 64
#define NB 2
#define M_TOT 4096  // NB*S_LEN

typedef __bf16 bf16x8 __attribute__((ext_vector_type(8)));
typedef float f32x4 __attribute__((ext_vector_type(4)));
typedef unsigned short u16;

__device__ __forceinline__ u16 f2bf(float f) {
  union { float f; unsigned u; } v; v.f = f;
  unsigned r = v.u + 0x7FFFu + ((v.u >> 16) & 1u);
  return (u16)(r >> 16);
}

__device__ __forceinline__ u16 f2bf_trunc(float f) {
  union { float f; unsigned u; } v; v.f = f;
  return (u16)(v.u >> 16);
}

__device__ __forceinline__ f32x4 mfma16(bf16x8 a, bf16x8 b, f32x4 c) {
  return __builtin_amdgcn_mfma_f32_16x16x32_bf16(a, b, c, 0, 0, 0);
}

// async global->LDS 16B: lds dest is wave-uniform base + lane*16
__device__ __forceinline__ void gll16(const u16* g, u16* l) {
  __builtin_amdgcn_global_load_lds(
      (const __attribute__((address_space(1))) unsigned int*)g,
      (__attribute__((address_space(3))) unsigned int*)l, 16, 0, 0);
}

// ---- cast fp32 -> bf16, 4 elems/thread ----
__global__ void __launch_bounds__(256) cast_kernel(const float* __restrict__ in,
                                                   u16* __restrict__ out) {
  int i = (blockIdx.x * 256 + threadIdx.x) * 4;
  float4 v = *(const float4*)(in + i);
  ushort4 o;
  o.x = f2bf(v.x); o.y = f2bf(v.y); o.z = f2bf(v.z); o.w = f2bf(v.w);
  *(ushort4*)(out + i) = o;
}

// ---- rope table: tab[(b*S+s)*32 + p] = (sin, cos) ----
__global__ void __launch_bounds__(256) rope_table_kernel(const int* __restrict__ positions,
                                                         float2* __restrict__ tab) {
  int idx = blockIdx.x * 256 + threadIdx.x;  // < NB*S_LEN*32
  int p = idx & 31;
  int bs = idx >> 5;
  float pos = (float)positions[bs];
  float ang = pos / __powf(10000.0f, (float)p * (1.0f / 32.0f));
  float sn, cs;
  sincosf(ang, &sn, &cs);
  tab[idx] = make_float2(sn, cs);
}

// ---- weight transpose + cast: Wt[n][k] = W[k][n] ----
__global__ void __launch_bounds__(256) wtrans_kernel(const float* __restrict__ W,
                                                     u16* __restrict__ Wt) {
  __shared__ float t[32][33];
  int n0 = blockIdx.x * 32, k0 = blockIdx.y * 32;
  int tx = threadIdx.x, ty0 = threadIdx.y;
#pragma unroll
  for (int i = 0; i < 4; i++) {
    int ty = ty0 + i * 8;
    t[ty][tx] = W[(size_t)(k0 + ty) * NF + n0 + tx];
  }
  __syncthreads();
#pragma unroll
  for (int i = 0; i < 4; i++) {
    int ty = ty0 + i * 8;
    Wt[(size_t)(n0 + ty) * NF + k0 + tx] = f2bf(t[tx][ty]);
  }
}

// 128x128 tile bf16 GEMM core: C = A[M,K] * Bt[N,K]^T, K=1024.
// Unpadded [128][32] u16 tiles staged via global_load_lds (m97 pattern).
__device__ __forceinline__ void mm_core(const u16* __restrict__ A, const u16* __restrict__ Bt,
                                        int m0, int n0, u16* As, u16* Bs, f32x4 acc[4][4]) {
  const int tid = threadIdx.x;
  const int lane = tid & 63, w = tid >> 6;
  const int l15 = lane & 15, quad = lane >> 4;
  const int wr = w >> 1, wc = w & 1;
#pragma unroll
  for (int i = 0; i < 4; i++)
#pragma unroll
    for (int j = 0; j < 4; j++) {
      f32x4 z = {0.f, 0.f, 0.f, 0.f};
      acc[i][j] = z;
    }
  for (int k0 = 0; k0 < NF; k0 += 32) {
    __syncthreads();  // prior tile's reads done before overwrite
#pragma unroll
    for (int i = 0; i < 2; i++) {
      int ci = (w * 2 + i) * 64 + lane;  // chunk index in [0,512)
      int row = ci >> 2, c = ci & 3;
      gll16(&A[(size_t)(m0 + row) * NF + k0 + c * 8], &As[(w * 2 + i) * 512]);
      gll16(&Bt[(size_t)(n0 + row) * NF + k0 + c * 8], &Bs[(w * 2 + i) * 512]);
    }
    __syncthreads();  // drains vmcnt: tiles staged
    bf16x8 af[4], bfr[4];
#pragma unroll
    for (int i = 0; i < 4; i++)
      af[i] = *(const bf16x8*)&As[(wr * 64 + i * 16 + l15) * 32 + quad * 8];
#pragma unroll
    for (int j = 0; j < 4; j++)
      bfr[j] = *(const bf16x8*)&Bs[(wc * 64 + j * 16 + l15) * 32 + quad * 8];
#pragma unroll
    for (int i = 0; i < 4; i++)
#pragma unroll
      for (int j = 0; j < 4; j++)
        acc[i][j] = mfma16(af[i], bfr[j], acc[i][j]);
  }
}

#define QSCL 0.18033688f  // 0.125 * log2(e): folds score scale + exp->exp2 into q

// ---- fused QKV projection: z=0 -> q (rope, scaled), z=1 -> k (rope), z=2 -> v (transposed) ----
__global__ void __launch_bounds__(256) gemm_qkv_kernel(
    const u16* __restrict__ xb,
    const u16* __restrict__ wtq, const u16* __restrict__ wtk, const u16* __restrict__ wtv,
    const float* __restrict__ bq, const float* __restrict__ bk, const float* __restrict__ bv,
    const float2* __restrict__ rtab,
    u16* __restrict__ qo, u16* __restrict__ ko, u16* __restrict__ vto) {
  __shared__ u16 As[128 * 32], Bs[128 * 32];
  const int z = blockIdx.z;
  const u16* Wt = (z == 0) ? wtq : (z == 1) ? wtk : wtv;
  const float* bias = (z == 0) ? bq : (z == 1) ? bk : bv;
  const int m0 = blockIdx.y * 128, n0 = blockIdx.x * 128;
  f32x4 acc[4][4];
  mm_core(xb, Wt, m0, n0, As, Bs, acc);
  const int tid = threadIdx.x;
  const int lane = tid & 63, w = tid >> 6;
  const int l15 = lane & 15, quad = lane >> 4;
  const int wr = w >> 1, wc = w & 1;
  if (z < 2) {
    u16* out = (z == 0) ? qo : ko;
    const float oscl = (z == 0) ? QSCL : 1.0f;
#pragma unroll
    for (int i = 0; i < 4; i++) {
#pragma unroll
      for (int r = 0; r < 4; r++) {
        int gm = m0 + wr * 64 + i * 16 + quad * 4 + r;  // = b*S + s
        int b = gm >> 11, s = gm & 2047;
#pragma unroll
        for (int j = 0; j < 2; j++) {
          int col1 = n0 + wc * 64 + j * 16 + l15;
          int p = j * 16 + l15;
          float2 sc = rtab[gm * 32 + p];
          float x1 = acc[i][j][r] + bias[col1];
          float x2 = acc[i][j + 2][r] + bias[col1 + 32];
          float o1 = (x1 * sc.y - x2 * sc.x) * oscl;
          float o2 = (x2 * sc.y + x1 * sc.x) * oscl;
          int h = col1 >> 6;
          size_t base = ((size_t)((b * NH + h) * S_LEN + s)) * HD;
          out[base + p] = f2bf(o1);
          out[base + p + 32] = f2bf(o2);
        }
      }
    }
  } else {
    // v: write transposed [bh][d][s]
#pragma unroll
    for (int i = 0; i < 4; i++) {
      int gm0 = m0 + wr * 64 + i * 16 + quad * 4;
      int b = gm0 >> 11, s0 = gm0 & 2047;
#pragma unroll
      for (int j = 0; j < 4; j++) {
        int col = n0 + wc * 64 + j * 16 + l15;
        int h = col >> 6, d = col & 63;
        float bb = bias[col];
        ushort4 pk;
        pk.x = f2bf(acc[i][j][0] + bb);
        pk.y = f2bf(acc[i][j][1] + bb);
        pk.z = f2bf(acc[i][j][2] + bb);
        pk.w = f2bf(acc[i][j][3] + bb);
        *(ushort4*)&vto[((size_t)((b * NH + h) * HD + d)) * S_LEN + s0] = pk;
      }
    }
  }
}

// ---- output projection: fp32 out ----
__global__ void __launch_bounds__(256) gemm_o_kernel(const u16* __restrict__ ab,
                                                     const u16* __restrict__ wto,
                                                     const float* __restrict__ bo,
                                                     float* __restrict__ out) {
  __shared__ u16 As[128 * 32], Bs[128 * 32];
  const int m0 = blockIdx.y * 128, n0 = blockIdx.x * 128;
  f32x4 acc[4][4];
  mm_core(ab, wto, m0, n0, As, Bs, acc);
  const int tid = threadIdx.x;
  const int lane = tid & 63, w = tid >> 6;
  const int l15 = lane & 15, quad = lane >> 4;
  const int wr = w >> 1, wc = w & 1;
#pragma unroll
  for (int i = 0; i < 4; i++) {
#pragma unroll
    for (int j = 0; j < 4; j++) {
      int col = n0 + wc * 64 + j * 16 + l15;
      float bb = bo[col];
#pragma unroll
      for (int r = 0; r < 4; r++) {
        int gm = m0 + wr * 64 + i * 16 + quad * 4 + r;
        out[(size_t)gm * NF + col] = acc[i][j][r] + bb;
      }
    }
  }
}

// ---- flash attention, causal ----
// Pairing: block p handles q-tiles p and 31-p sequentially -> uniform 33 k-iterations.
// K/V double-buffered (1 barrier/iter, register prefetch). l accumulated via ones-row
// MFMA (auto-rescales with alpha). exp2-domain softmax (scale folded into q).
#define KAP 72
#define VAP 72

__global__ void __launch_bounds__(256) attn_kernel(const u16* __restrict__ qb,
                                                   const u16* __restrict__ kb,
                                                   const u16* __restrict__ vtb,
                                                   u16* __restrict__ ob) {
  __shared__ u16 ks[2][64 * KAP];
  __shared__ u16 vs[2][80 * VAP];  // rows 0..63: V^T[d][s]; row 64: ones; 65..79: zero
  __shared__ u16 ps[4][16 * KAP];  // per-wave P relayout (wave-local, no barrier)
  const int p = blockIdx.x, bh = blockIdx.y;
  const int tid = threadIdx.x;
  const int lane = tid & 63, w = tid >> 6, l15 = lane & 15, quad = lane >> 4;
  const int bb = bh >> 4, h = bh & 15;

  // init aux rows of vs (both buffers), once
  for (int i = tid; i < 2 * 16 * VAP; i += 256) {
    int bsel = (i >= 16 * VAP);
    int r = i - bsel * 16 * VAP;
    int rr = r / VAP, cc = r % VAP;
    vs[bsel][(64 + rr) * VAP + cc] = (rr == 0 && cc < 64) ? (u16)0x3F80 : (u16)0;
  }

  const size_t kvbase = (size_t)bh * S_LEN;
  const size_t vbase = (size_t)bh * HD;
  const int c1 = tid + 256;
  const int kr0 = tid >> 3, kc0 = (tid & 7) * 8;
  const int kr1 = c1 >> 3, kc1 = (c1 & 7) * 8;
  const int rowl = w * 16 + quad * 4;  // this lane's first q-row (local to tile)

  for (int ph = 0; ph < 2; ph++) {
    const int qt = ph ? (31 - p) : p;
    const int q0 = qt * 64;
    // Q fragments direct from global (A-layout: m=l15, k=quad*8+j)
    const u16* qrow = &qb[(kvbase + q0 + w * 16 + l15) * HD];
    bf16x8 aq0 = *(const bf16x8*)&qrow[quad * 8];
    bf16x8 aq1 = *(const bf16x8*)&qrow[32 + quad * 8];

    float mrun[4];
    f32x4 Oa[4], lacc;
#pragma unroll
    for (int r = 0; r < 4; r++) mrun[r] = -1e30f;
#pragma unroll
    for (int t = 0; t < 4; t++) { f32x4 z = {0.f, 0.f, 0.f, 0.f}; Oa[t] = z; }
    { f32x4 z = {0.f, 0.f, 0.f, 0.f}; lacc = z; }

    __syncthreads();  // prior phase's LDS reads done (also covers aux init for ph=0)
    *(uint4*)&ks[0][kr0 * KAP + kc0] = *(const uint4*)&kb[(kvbase + kr0) * HD + kc0];
    *(uint4*)&ks[0][kr1 * KAP + kc1] = *(const uint4*)&kb[(kvbase + kr1) * HD + kc1];
    *(uint4*)&vs[0][kr0 * VAP + kc0] = *(const uint4*)&vtb[(vbase + kr0) * S_LEN + q0 * 0 + kc0];
    *(uint4*)&vs[0][kr1 * VAP + kc1] = *(const uint4*)&vtb[(vbase + kr1) * S_LEN + q0 * 0 + kc1];
    __syncthreads();

    for (int kt = 0; kt <= qt; kt++) {
      const int bsel = kt & 1;
      uint4 pk0, pk1, pv0, pv1;
      if (kt < qt) {  // prefetch next K/V tile into registers (overlaps compute)
        int k1 = (kt + 1) * 64;
        pk0 = *(const uint4*)&kb[(kvbase + k1 + kr0) * HD + kc0];
        pk1 = *(const uint4*)&kb[(kvbase + k1 + kr1) * HD + kc1];
        pv0 = *(const uint4*)&vtb[(vbase + kr0) * S_LEN + k1 + kc0];
        pv1 = *(const uint4*)&vtb[(vbase + kr1) * S_LEN + k1 + kc1];
      }
      // QK^T (already exp2-scaled via q)
      f32x4 sf[4];
#pragma unroll
      for (int t = 0; t < 4; t++) {
        bf16x8 bk0 = *(const bf16x8*)&ks[bsel][(t * 16 + l15) * KAP + quad * 8];
        bf16x8 bk1 = *(const bf16x8*)&ks[bsel][(t * 16 + l15) * KAP + 32 + quad * 8];
        f32x4 zz = {0.f, 0.f, 0.f, 0.f};
        zz = mfma16(aq0, bk0, zz);
        zz = mfma16(aq1, bk1, zz);
        sf[t] = zz;
      }
      if (kt == qt) {  // causal mask on the diagonal tile
#pragma unroll
        for (int t = 0; t < 4; t++)
#pragma unroll
          for (int r = 0; r < 4; r++)
            if (t * 16 + l15 > rowl + r) sf[t][r] = -1e30f;
      }
      // online softmax, exp2 domain; only the max needs a cross-lane reduce
      float alph[4];
#pragma unroll
      for (int r = 0; r < 4; r++) {
        float mx = fmaxf(fmaxf(sf[0][r], sf[1][r]), fmaxf(sf[2][r], sf[3][r]));
#pragma unroll
        for (int off = 1; off < 16; off <<= 1) mx = fmaxf(mx, __shfl_xor(mx, off, 64));
        float mnew = fmaxf(mrun[r], mx);
        alph[r] = __builtin_amdgcn_exp2f(mrun[r] - mnew);
        mrun[r] = mnew;
#pragma unroll
        for (int t = 0; t < 4; t++)
          sf[t][r] = __builtin_amdgcn_exp2f(sf[t][r] - mnew);
      }
#pragma unroll
      for (int t = 0; t < 4; t++)
#pragma unroll
        for (int r = 0; r < 4; r++) Oa[t][r] *= alph[r];
#pragma unroll
      for (int r = 0; r < 4; r++) lacc[r] *= alph[r];
      // P: C-layout -> wave-local LDS -> A-layout (no block barrier needed)
#pragma unroll
      for (int t = 0; t < 4; t++)
#pragma unroll
        for (int r = 0; r < 4; r++)
          ps[w][(quad * 4 + r) * KAP + t * 16 + l15] = f2bf_trunc(sf[t][r]);
      __builtin_amdgcn_wave_barrier();
      bf16x8 ap0 = *(const bf16x8*)&ps[w][l15 * KAP + quad * 8];
      bf16x8 ap1 = *(const bf16x8*)&ps[w][l15 * KAP + 32 + quad * 8];
      // PV (+ l from ones-row: rescales with alpha like any output column)
#pragma unroll
      for (int t = 0; t < 4; t++) {
        bf16x8 bv0 = *(const bf16x8*)&vs[bsel][(t * 16 + l15) * VAP + quad * 8];
        bf16x8 bv1 = *(const bf16x8*)&vs[bsel][(t * 16 + l15) * VAP + 32 + quad * 8];
        Oa[t] = mfma16(ap0, bv0, Oa[t]);
        Oa[t] = mfma16(ap1, bv1, Oa[t]);
      }
      {
        bf16x8 bl0 = *(const bf16x8*)&vs[bsel][(64 + l15) * VAP + quad * 8];
        bf16x8 bl1 = *(const bf16x8*)&vs[bsel][(64 + l15) * VAP + 32 + quad * 8];
        lacc = mfma16(ap0, bl0, lacc);
        lacc = mfma16(ap1, bl1, lacc);
      }
      if (kt < qt) {  // commit prefetched tile to the other buffer
        *(uint4*)&ks[bsel ^ 1][kr0 * KAP + kc0] = pk0;
        *(uint4*)&ks[bsel ^ 1][kr1 * KAP + kc1] = pk1;
        *(uint4*)&vs[bsel ^ 1][kr0 * VAP + kc0] = pv0;
        *(uint4*)&vs[bsel ^ 1][kr1 * VAP + kc1] = pv1;
      }
      __syncthreads();
    }
    // epilogue: l lives on lane l15==0 of each quad (reg r = row quad*4+r)
#pragma unroll
    for (int r = 0; r < 4; r++) {
      float lr = __shfl(lacc[r], lane & 48, 64);
      float inv = 1.f / lr;
      int sq = q0 + rowl + r;
      size_t rowb = ((size_t)(bb * S_LEN + sq)) * NF + h * HD;
#pragma unroll
      for (int t = 0; t < 4; t++)
        ob[rowb + t * 16 + l15] = f2bf(Oa[t][r] * inv);
    }
  }
}

extern "C" void kernel_launch(void* const* d_in, const int* in_sizes, int n_in,
                              void* d_out, int out_size, void* d_ws, size_t ws_size,
                              hipStream_t stream) {
  const float* x  = (const float*)d_in[0];
  const int* pos  = (const int*)d_in[1];
  const float* Wq = (const float*)d_in[2];
  const float* bq = (const float*)d_in[3];
  const float* Wk = (const float*)d_in[4];
  const float* bk = (const float*)d_in[5];
  const float* Wv = (const float*)d_in[6];
  const float* bv = (const float*)d_in[7];
  const float* Wo = (const float*)d_in[8];
  const float* bo = (const float*)d_in[9];
  float* out = (float*)d_out;

  u16* xb  = (u16*)d_ws;                    // [M][F] bf16, reused later as attn out
  u16* wtq = xb + (size_t)M_TOT * NF;
  u16* wtk = wtq + (size_t)NF * NF;
  u16* wtv = wtk + (size_t)NF * NF;
  u16* wto = wtv + (size_t)NF * NF;
  u16* qb  = wto + (size_t)NF * NF;         // [bh][s][d] (pre-scaled by 0.125*log2e)
  u16* kb  = qb + (size_t)M_TOT * NF;       // [bh][s][d]
  u16* vtb = kb + (size_t)M_TOT * NF;       // [bh][d][s]
  float2* rtab = (float2*)(vtb + (size_t)M_TOT * NF);
  u16* attnb = xb;  // alias: xb no longer needed after QKV GEMM

  cast_kernel<<<dim3(M_TOT * NF / 1024), 256, 0, stream>>>(x, xb);
  rope_table_kernel<<<dim3(NB * S_LEN * 32 / 256), 256, 0, stream>>>(pos, rtab);
  wtrans_kernel<<<dim3(32, 32), dim3(32, 8), 0, stream>>>(Wq, wtq);
  wtrans_kernel<<<dim3(32, 32), dim3(32, 8), 0, stream>>>(Wk, wtk);
  wtrans_kernel<<<dim3(32, 32), dim3(32, 8), 0, stream>>>(Wv, wtv);
  wtrans_kernel<<<dim3(32, 32), dim3(32, 8), 0, stream>>>(Wo, wto);
  gemm_qkv_kernel<<<dim3(8, 32, 3), 256, 0, stream>>>(xb, wtq, wtk, wtv, bq, bk, bv,
                                                      rtab, qb, kb, vtb);
  attn_kernel<<<dim3(16, 32), 256, 0, stream>>>(qb, kb, vtb, attnb);
  gemm_o_kernel<<<dim3(8, 32), 256, 0, stream>>>(attnb, wto, bo, out);
}

// Round 3
// 231.059 us; speedup vs baseline: 1.3265x; 1.0450x over previous
//
#include <hip/hip_runtime.h>
#include <hip/hip_bf16.h>

#define S_LEN 2048
#define NF 1024
#define NH 16
#define HD 64
#define NB 2
#define M_TOT 4096  // NB*S_LEN

typedef __bf16 bf16x8 __attribute__((ext_vector_type(8)));
typedef float f32x4 __attribute__((ext_vector_type(4)));
typedef unsigned short u16;

__device__ __forceinline__ u16 f2bf(float f) {
  union { float f; unsigned u; } v; v.f = f;
  unsigned r = v.u + 0x7FFFu + ((v.u >> 16) & 1u);
  return (u16)(r >> 16);
}

__device__ __forceinline__ unsigned pk2bf(float a, float b) {
  __hip_bfloat162 t = __float22bfloat162_rn(make_float2(a, b));
  union { __hip_bfloat162 h; unsigned u; } u; u.h = t; return u.u;
}

__device__ __forceinline__ f32x4 mfma16(bf16x8 a, bf16x8 b, f32x4 c) {
  return __builtin_amdgcn_mfma_f32_16x16x32_bf16(a, b, c, 0, 0, 0);
}

// async global->LDS 16B: lds dest is wave-uniform base + lane*16
__device__ __forceinline__ void gll16(const u16* g, u16* l) {
  __builtin_amdgcn_global_load_lds(
      (const __attribute__((address_space(1))) unsigned int*)g,
      (__attribute__((address_space(3))) unsigned int*)l, 16, 0, 0);
}

// XOR-swizzled LDS addressing: 64-u16 rows (128 B = 8 chunks of 16 B),
// chunk' = chunk ^ (row&7) -> even 8-lane spread per 16B-column for both
// the (row=l15-based, chunk=quad-based) fragment reads and staging writes.
__device__ __forceinline__ u16* swz(u16* base, int row, int chunk) {
  return (u16*)((char*)base + row * 128 + ((chunk ^ (row & 7)) * 16));
}
__device__ __forceinline__ const u16* swz(const u16* base, int row, int chunk) {
  return (const u16*)((const char*)base + row * 128 + ((chunk ^ (row & 7)) * 16));
}

// ---- cast fp32 -> bf16, 4 elems/thread ----
__global__ void __launch_bounds__(256) cast_kernel(const float* __restrict__ in,
                                                   u16* __restrict__ out) {
  int i = (blockIdx.x * 256 + threadIdx.x) * 4;
  float4 v = *(const float4*)(in + i);
  ushort4 o;
  o.x = f2bf(v.x); o.y = f2bf(v.y); o.z = f2bf(v.z); o.w = f2bf(v.w);
  *(ushort4*)(out + i) = o;
}

// ---- rope table: tab[(b*S+s)*32 + p] = (sin, cos) ----
__global__ void __launch_bounds__(256) rope_table_kernel(const int* __restrict__ positions,
                                                         float2* __restrict__ tab) {
  int idx = blockIdx.x * 256 + threadIdx.x;  // < NB*S_LEN*32
  int p = idx & 31;
  int bs = idx >> 5;
  float pos = (float)positions[bs];
  float ang = pos / __powf(10000.0f, (float)p * (1.0f / 32.0f));
  float sn, cs;
  sincosf(ang, &sn, &cs);
  tab[idx] = make_float2(sn, cs);
}

// ---- weight transpose + cast (all 4 weights in one dispatch): Wt[n][k] = W[k][n] ----
__global__ void __launch_bounds__(256) wtrans_kernel(
    const float* __restrict__ W0, const float* __restrict__ W1,
    const float* __restrict__ W2, const float* __restrict__ W3,
    u16* __restrict__ T0, u16* __restrict__ T1,
    u16* __restrict__ T2, u16* __restrict__ T3) {
  const float* W = (blockIdx.z == 0) ? W0 : (blockIdx.z == 1) ? W1 : (blockIdx.z == 2) ? W2 : W3;
  u16* Wt = (blockIdx.z == 0) ? T0 : (blockIdx.z == 1) ? T1 : (blockIdx.z == 2) ? T2 : T3;
  __shared__ float t[32][33];
  int n0 = blockIdx.x * 32, k0 = blockIdx.y * 32;
  int tx = threadIdx.x, ty0 = threadIdx.y;
#pragma unroll
  for (int i = 0; i < 4; i++) {
    int ty = ty0 + i * 8;
    t[ty][tx] = W[(size_t)(k0 + ty) * NF + n0 + tx];
  }
  __syncthreads();
#pragma unroll
  for (int i = 0; i < 4; i++) {
    int ty = ty0 + i * 8;
    Wt[(size_t)(n0 + ty) * NF + k0 + tx] = f2bf(t[tx][ty]);
  }
}

// 128x128 tile bf16 GEMM core: C = A[M,K] * Bt[N,K]^T, K=1024.
// Unpadded [128][32] u16 tiles staged via global_load_lds (m97 pattern).
__device__ __forceinline__ void mm_core(const u16* __restrict__ A, const u16* __restrict__ Bt,
                                        int m0, int n0, u16* As, u16* Bs, f32x4 acc[4][4]) {
  const int tid = threadIdx.x;
  const int lane = tid & 63, w = tid >> 6;
  const int l15 = lane & 15, quad = lane >> 4;
  const int wr = w >> 1, wc = w & 1;
#pragma unroll
  for (int i = 0; i < 4; i++)
#pragma unroll
    for (int j = 0; j < 4; j++) {
      f32x4 z = {0.f, 0.f, 0.f, 0.f};
      acc[i][j] = z;
    }
  for (int k0 = 0; k0 < NF; k0 += 32) {
    __syncthreads();  // prior tile's reads done before overwrite
#pragma unroll
    for (int i = 0; i < 2; i++) {
      int ci = (w * 2 + i) * 64 + lane;  // chunk index in [0,512)
      int row = ci >> 2, c = ci & 3;
      gll16(&A[(size_t)(m0 + row) * NF + k0 + c * 8], &As[(w * 2 + i) * 512]);
      gll16(&Bt[(size_t)(n0 + row) * NF + k0 + c * 8], &Bs[(w * 2 + i) * 512]);
    }
    __syncthreads();  // drains vmcnt: tiles staged
    bf16x8 af[4], bfr[4];
#pragma unroll
    for (int i = 0; i < 4; i++)
      af[i] = *(const bf16x8*)&As[(wr * 64 + i * 16 + l15) * 32 + quad * 8];
#pragma unroll
    for (int j = 0; j < 4; j++)
      bfr[j] = *(const bf16x8*)&Bs[(wc * 64 + j * 16 + l15) * 32 + quad * 8];
#pragma unroll
    for (int i = 0; i < 4; i++)
#pragma unroll
      for (int j = 0; j < 4; j++)
        acc[i][j] = mfma16(af[i], bfr[j], acc[i][j]);
  }
}

#define QSCL 0.18033688f  // 0.125 * log2(e): folds score scale + exp->exp2 into q

// ---- fused QKV projection: z=0 -> q (rope, scaled), z=1 -> k (rope), z=2 -> v (transposed) ----
__global__ void __launch_bounds__(256) gemm_qkv_kernel(
    const u16* __restrict__ xb,
    const u16* __restrict__ wtq, const u16* __restrict__ wtk, const u16* __restrict__ wtv,
    const float* __restrict__ bq, const float* __restrict__ bk, const float* __restrict__ bv,
    const float2* __restrict__ rtab,
    u16* __restrict__ qo, u16* __restrict__ ko, u16* __restrict__ vto) {
  __shared__ u16 As[128 * 32], Bs[128 * 32];
  const int z = blockIdx.z;
  const u16* Wt = (z == 0) ? wtq : (z == 1) ? wtk : wtv;
  const float* bias = (z == 0) ? bq : (z == 1) ? bk : bv;
  const int m0 = blockIdx.y * 128, n0 = blockIdx.x * 128;
  f32x4 acc[4][4];
  mm_core(xb, Wt, m0, n0, As, Bs, acc);
  const int tid = threadIdx.x;
  const int lane = tid & 63, w = tid >> 6;
  const int l15 = lane & 15, quad = lane >> 4;
  const int wr = w >> 1, wc = w & 1;
  if (z < 2) {
    u16* out = (z == 0) ? qo : ko;
    const float oscl = (z == 0) ? QSCL : 1.0f;
#pragma unroll
    for (int i = 0; i < 4; i++) {
#pragma unroll
      for (int r = 0; r < 4; r++) {
        int gm = m0 + wr * 64 + i * 16 + quad * 4 + r;  // = b*S + s
        int b = gm >> 11, s = gm & 2047;
#pragma unroll
        for (int j = 0; j < 2; j++) {
          int col1 = n0 + wc * 64 + j * 16 + l15;
          int p = j * 16 + l15;
          float2 sc = rtab[gm * 32 + p];
          float x1 = acc[i][j][r] + bias[col1];
          float x2 = acc[i][j + 2][r] + bias[col1 + 32];
          float o1 = (x1 * sc.y - x2 * sc.x) * oscl;
          float o2 = (x2 * sc.y + x1 * sc.x) * oscl;
          int h = col1 >> 6;
          size_t base = ((size_t)((b * NH + h) * S_LEN + s)) * HD;
          out[base + p] = f2bf(o1);
          out[base + p + 32] = f2bf(o2);
        }
      }
    }
  } else {
    // v: write transposed [bh][d][s]
#pragma unroll
    for (int i = 0; i < 4; i++) {
      int gm0 = m0 + wr * 64 + i * 16 + quad * 4;
      int b = gm0 >> 11, s0 = gm0 & 2047;
#pragma unroll
      for (int j = 0; j < 4; j++) {
        int col = n0 + wc * 64 + j * 16 + l15;
        int h = col >> 6, d = col & 63;
        float bb = bias[col];
        ushort4 pk;
        pk.x = f2bf(acc[i][j][0] + bb);
        pk.y = f2bf(acc[i][j][1] + bb);
        pk.z = f2bf(acc[i][j][2] + bb);
        pk.w = f2bf(acc[i][j][3] + bb);
        *(ushort4*)&vto[((size_t)((b * NH + h) * HD + d)) * S_LEN + s0] = pk;
      }
    }
  }
}

// ---- output projection: fp32 out ----
__global__ void __launch_bounds__(256) gemm_o_kernel(const u16* __restrict__ ab,
                                                     const u16* __restrict__ wto,
                                                     const float* __restrict__ bo,
                                                     float* __restrict__ out) {
  __shared__ u16 As[128 * 32], Bs[128 * 32];
  const int m0 = blockIdx.y * 128, n0 = blockIdx.x * 128;
  f32x4 acc[4][4];
  mm_core(ab, wto, m0, n0, As, Bs, acc);
  const int tid = threadIdx.x;
  const int lane = tid & 63, w = tid >> 6;
  const int l15 = lane & 15, quad = lane >> 4;
  const int wr = w >> 1, wc = w & 1;
#pragma unroll
  for (int i = 0; i < 4; i++) {
#pragma unroll
    for (int j = 0; j < 4; j++) {
      int col = n0 + wc * 64 + j * 16 + l15;
      float bb = bo[col];
#pragma unroll
      for (int r = 0; r < 4; r++) {
        int gm = m0 + wr * 64 + i * 16 + quad * 4 + r;
        out[(size_t)gm * NF + col] = acc[i][j][r] + bb;
      }
    }
  }
}

// ---- flash attention, causal, S^T formulation ----
// Per block: 128 q-rows (32/wave x 4 waves), 64-col k-tiles, K/V double-buffered
// (register prefetch, 1 barrier/iter). S^T = K.Q^T so the score C-layout has
// col=q, consecutive-regs=consecutive s -> P packs to b64 writes and enters PV
// as the A operand naturally. Row softmax = in-lane reduce + 2 shuffles.
// XOR-swizzled LDS, no pads, conflict-free b128.
__global__ void __launch_bounds__(256) attn_kernel(const u16* __restrict__ qb,
                                                   const u16* __restrict__ kb,
                                                   const u16* __restrict__ vtb,
                                                   u16* __restrict__ ob) {
  __shared__ u16 ks[2][64 * 64];
  __shared__ u16 vs[2][64 * 64];
  __shared__ u16 ps[4][32 * 64];
  const int bx = blockIdx.x;
  // descending-qt pairing under round-robin dispatch: blocks i and i+256 have
  // qt summing to 15 -> uniform per-CU work (heuristic only, not correctness)
  const int qt = (bx < 256) ? (15 - (bx >> 5)) : ((bx - 256) >> 5);
  const int bh = bx & 31;
  const int tid = threadIdx.x;
  const int lane = tid & 63, w = tid >> 6, l15 = lane & 15, quad = lane >> 4;
  const int bb = bh >> 4, h = bh & 15;
  const size_t kvbase = (size_t)bh * S_LEN;
  const size_t vbase = (size_t)bh * HD;
  const int Q0 = qt * 128;
  const int nit = 2 * (qt + 1);
  // staging: 512 16B-chunks over 256 threads
  const int r0 = tid >> 3, c0 = tid & 7;
  const int r1 = r0 + 32;

  // Q fragments (B-operand: col=l15=q, k=quad*8+j=d — bytes identical to A-layout)
  bf16x8 qf[2][2];
#pragma unroll
  for (int c = 0; c < 2; c++) {
    const u16* qrow = &qb[(kvbase + Q0 + w * 32 + c * 16 + l15) * HD];
#pragma unroll
    for (int hh = 0; hh < 2; hh++)
      qf[c][hh] = *(const bf16x8*)&qrow[hh * 32 + quad * 8];
  }

  float mrun[2] = {-1e30f, -1e30f}, lrun[2] = {0.f, 0.f};
  f32x4 Oa[2][4];
#pragma unroll
  for (int g = 0; g < 2; g++)
#pragma unroll
    for (int t = 0; t < 4; t++) { f32x4 z = {0.f, 0.f, 0.f, 0.f}; Oa[g][t] = z; }

  // stage tile 0
  *(uint4*)swz(ks[0], r0, c0) = *(const uint4*)&kb[(kvbase + r0) * HD + c0 * 8];
  *(uint4*)swz(ks[0], r1, c0) = *(const uint4*)&kb[(kvbase + r1) * HD + c0 * 8];
  *(uint4*)swz(vs[0], r0, c0) = *(const uint4*)&vtb[(vbase + r0) * S_LEN + c0 * 8];
  *(uint4*)swz(vs[0], r1, c0) = *(const uint4*)&vtb[(vbase + r1) * S_LEN + c0 * 8];
  __syncthreads();

  for (int it = 0; it < nit; ++it) {
    const int bsel = it & 1;
    const int k0 = it * 64;
    uint4 pk0, pk1, pv0, pv1;
    const bool pf = (it + 1 < nit);
    if (pf) {  // register prefetch of next K/V tile (overlaps compute)
      int k1 = k0 + 64;
      pk0 = *(const uint4*)&kb[(kvbase + k1 + r0) * HD + c0 * 8];
      pk1 = *(const uint4*)&kb[(kvbase + k1 + r1) * HD + c0 * 8];
      pv0 = *(const uint4*)&vtb[(vbase + r0) * S_LEN + k1 + c0 * 8];
      pv1 = *(const uint4*)&vtb[(vbase + r1) * S_LEN + k1 + c0 * 8];
    }
    // S^T = K.Q^T : per wave 64s x 32q
    f32x4 sf[2][4];
#pragma unroll
    for (int t = 0; t < 4; t++) {
      bf16x8 ak0 = *(const bf16x8*)swz(ks[bsel], t * 16 + l15, quad);
      bf16x8 ak1 = *(const bf16x8*)swz(ks[bsel], t * 16 + l15, 4 + quad);
#pragma unroll
      for (int c = 0; c < 2; c++) {
        f32x4 z = {0.f, 0.f, 0.f, 0.f};
        z = mfma16(ak0, qf[c][0], z);
        z = mfma16(ak1, qf[c][1], z);
        sf[c][t] = z;
      }
    }
    if (it >= 2 * qt) {  // causal mask only on the last two (diagonal) tiles
#pragma unroll
      for (int c = 0; c < 2; c++) {
        int qg = Q0 + w * 32 + c * 16 + l15;
#pragma unroll
        for (int t = 0; t < 4; t++)
#pragma unroll
          for (int r = 0; r < 4; r++)
            if (k0 + t * 16 + quad * 4 + r > qg) sf[c][t][r] = -1e30f;
      }
    }
    // online softmax per q (lane-local column): in-lane reduce + 2 shuffles
    float alph[2];
#pragma unroll
    for (int c = 0; c < 2; c++) {
      float mx = sf[c][0][0];
#pragma unroll
      for (int t = 0; t < 4; t++)
#pragma unroll
        for (int r = 0; r < 4; r++) mx = fmaxf(mx, sf[c][t][r]);
      mx = fmaxf(mx, __shfl_xor(mx, 16, 64));
      mx = fmaxf(mx, __shfl_xor(mx, 32, 64));
      float mnew = fmaxf(mrun[c], mx);
      float al = __builtin_amdgcn_exp2f(mrun[c] - mnew);
      float rs = 0.f;
#pragma unroll
      for (int t = 0; t < 4; t++)
#pragma unroll
        for (int r = 0; r < 4; r++) {
          float e = __builtin_amdgcn_exp2f(sf[c][t][r] - mnew);
          sf[c][t][r] = e;
          rs += e;
        }
      rs += __shfl_xor(rs, 16, 64);
      rs += __shfl_xor(rs, 32, 64);
      lrun[c] = al * lrun[c] + rs;
      mrun[c] = mnew;
      alph[c] = al;
    }
    // O rescale only when some running max moved (wave-uniform branch)
    if (__any((alph[0] < 1.f) || (alph[1] < 1.f))) {
#pragma unroll
      for (int g = 0; g < 2; g++)
#pragma unroll
        for (int r = 0; r < 4; r++) {
          float ao = __shfl(alph[g], quad * 4 + r, 64);
#pragma unroll
          for (int t = 0; t < 4; t++) Oa[g][t][r] *= ao;
        }
    }
    // P -> LDS in A-layout [q][s], b64 packed (consecutive regs = consecutive s)
#pragma unroll
    for (int c = 0; c < 2; c++) {
      int row = c * 16 + l15;
#pragma unroll
      for (int t = 0; t < 4; t++) {
        uint2 pk;
        pk.x = pk2bf(sf[c][t][0], sf[c][t][1]);
        pk.y = pk2bf(sf[c][t][2], sf[c][t][3]);
        int chnk = 2 * t + (quad >> 1);
        *(uint2*)((char*)ps[w] + row * 128 + ((chnk ^ (row & 7)) * 16) + (quad & 1) * 8) = pk;
      }
    }
    __builtin_amdgcn_wave_barrier();  // wave-local LDS: DS ops are in-order per wave
    bf16x8 ap[2][2];
#pragma unroll
    for (int g = 0; g < 2; g++)
#pragma unroll
      for (int hh = 0; hh < 2; hh++)
        ap[g][hh] = *(const bf16x8*)swz(ps[w], g * 16 + l15, hh * 4 + quad);
    // O += P.V  (B-operand = V^T[d][s] rows)
#pragma unroll
    for (int t = 0; t < 4; t++) {
      bf16x8 bv0 = *(const bf16x8*)swz(vs[bsel], t * 16 + l15, quad);
      bf16x8 bv1 = *(const bf16x8*)swz(vs[bsel], t * 16 + l15, 4 + quad);
#pragma unroll
      for (int g = 0; g < 2; g++) {
        Oa[g][t] = mfma16(ap[g][0], bv0, Oa[g][t]);
        Oa[g][t] = mfma16(ap[g][1], bv1, Oa[g][t]);
      }
    }
    if (pf) {  // commit prefetched tile to the other buffer
      *(uint4*)swz(ks[bsel ^ 1], r0, c0) = pk0;
      *(uint4*)swz(ks[bsel ^ 1], r1, c0) = pk1;
      *(uint4*)swz(vs[bsel ^ 1], r0, c0) = pv0;
      *(uint4*)swz(vs[bsel ^ 1], r1, c0) = pv1;
    }
    __syncthreads();
  }
  // epilogue: O C-layout row = q(quad*4+r), col = d(l15); l lives at lane l15=q
#pragma unroll
  for (int g = 0; g < 2; g++) {
#pragma unroll
    for (int r = 0; r < 4; r++) {
      float lr = __shfl(lrun[g], quad * 4 + r, 64);
      float inv = 1.f / lr;
      int qg = Q0 + w * 32 + g * 16 + quad * 4 + r;
      size_t rowb = ((size_t)(bb * S_LEN + qg)) * NF + h * HD;
#pragma unroll
      for (int t = 0; t < 4; t++)
        ob[rowb + t * 16 + l15] = f2bf(Oa[g][t][r] * inv);
    }
  }
}

extern "C" void kernel_launch(void* const* d_in, const int* in_sizes, int n_in,
                              void* d_out, int out_size, void* d_ws, size_t ws_size,
                              hipStream_t stream) {
  const float* x  = (const float*)d_in[0];
  const int* pos  = (const int*)d_in[1];
  const float* Wq = (const float*)d_in[2];
  const float* bq = (const float*)d_in[3];
  const float* Wk = (const float*)d_in[4];
  const float* bk = (const float*)d_in[5];
  const float* Wv = (const float*)d_in[6];
  const float* bv = (const float*)d_in[7];
  const float* Wo = (const float*)d_in[8];
  const float* bo = (const float*)d_in[9];
  float* out = (float*)d_out;

  u16* xb  = (u16*)d_ws;                    // [M][F] bf16, reused later as attn out
  u16* wtq = xb + (size_t)M_TOT * NF;
  u16* wtk = wtq + (size_t)NF * NF;
  u16* wtv = wtk + (size_t)NF * NF;
  u16* wto = wtv + (size_t)NF * NF;
  u16* qb  = wto + (size_t)NF * NF;         // [bh][s][d] (pre-scaled by 0.125*log2e)
  u16* kb  = qb + (size_t)M_TOT * NF;       // [bh][s][d]
  u16* vtb = kb + (size_t)M_TOT * NF;       // [bh][d][s]
  float2* rtab = (float2*)(vtb + (size_t)M_TOT * NF);
  u16* attnb = xb;  // alias: xb no longer needed after QKV GEMM

  cast_kernel<<<dim3(M_TOT * NF / 1024), 256, 0, stream>>>(x, xb);
  rope_table_kernel<<<dim3(NB * S_LEN * 32 / 256), 256, 0, stream>>>(pos, rtab);
  wtrans_kernel<<<dim3(32, 32, 4), dim3(32, 8), 0, stream>>>(Wq, Wk, Wv, Wo,
                                                             wtq, wtk, wtv, wto);
  gemm_qkv_kernel<<<dim3(8, 32, 3), 256, 0, stream>>>(xb, wtq, wtk, wtv, bq, bk, bv,
                                                      rtab, qb, kb, vtb);
  attn_kernel<<<dim3(512), 256, 0, stream>>>(qb, kb, vtb, attnb);
  gemm_o_kernel<<<dim3(8, 32), 256, 0, stream>>>(attnb, wto, bo, out);
}